// Round 1
// baseline (1602.376 us; speedup 1.0000x reference)
//
#include <hip/hip_runtime.h>

#define TT 2000      // time steps
#define NBATCH 100
#define N1 100
#define N2 10
#define KIN 784

// ---------- math helpers (fast but ~1-2 ulp, matching fp32 reference closely) ----------
__device__ __forceinline__ float rcp_nr(float d) {
  float r = __builtin_amdgcn_rcpf(d);
  return r * (2.0f - d * r);          // one Newton step -> ~fp32 accurate
}
__device__ __forceinline__ float sigmoid3(float V) {
  // sigmoid((V - 20)/3)
  float x = (V - 20.0f) * (1.0f / 3.0f);
  return rcp_nr(1.0f + __expf(-x));
}
__device__ __forceinline__ float gate_u(float a, float b, float p) {
  float s = 0.005f * (a + b);                     // DT/2*(a+b)
  return (a * 0.01f + (1.0f - s) * p) * rcp_nr(s + 1.0f);
}
// One Crank-Nicolson HH step. Updates state in place.
__device__ __forceinline__ void hh_step(float& V, float& m, float& n, float& h,
                                        float& y, float zk) {
  float p1 = 40.0f * m * m * m * h;               // gna*m^3*h
  float nn2 = n * n;
  float p2 = 35.0f * nn2 * nn2;                   // gk*n^4
  float Gs = 0.005f * (p1 + p2 + 0.3f + 0.04f * y);
  float E = p1 * 55.0f + p2 * (-77.0f) + (0.3f * (-65.0f));   // gs*Vs*y == 0
  float Vn = (V * (1.0f - Gs) + 0.01f * (E + 1.5f)) * rcp_nr(1.0f + Gs);

  float eN  = __expf((25.0f - Vn) * (1.0f / 9.0f));
  float eBN = __expf((Vn - 25.0f) * (1.0f / 9.0f));
  float eM  = __expf((-Vn - 35.0f) * (1.0f / 9.0f));
  float eBM = __expf((Vn + 35.0f) * (1.0f / 9.0f));
  float aH  = 0.25f * __expf((-Vn - 90.0f) * (1.0f / 12.0f));
  float bH  = 0.25f * __expf((Vn + 34.0f) * (1.0f / 12.0f));
  float dN = 1.0f - eN, dBN = 1.0f - eBN, dM = 1.0f - eM, dBM = 1.0f - eBM;
  float aN = (dN  == 0.0f) ? 0.18f  :  0.02f  * (Vn - 25.0f) * rcp_nr(dN);
  float bN = (dBN == 0.0f) ? 0.018f : -0.002f * (Vn - 25.0f) * rcp_nr(dBN);
  float aM = (dM  == 0.0f) ? 1.638f :  0.182f * (Vn + 35.0f) * rcp_nr(dM);
  float bM = (dBM == 0.0f) ? 1.116f : -0.124f * (Vn + 35.0f) * rcp_nr(dBM);

  m = gate_u(aM, bM, m);
  n = gate_u(aN, bN, n);
  h = gate_u(aH, bH, h);
  y = gate_u(zk, 0.1f, y);                        // a_d*z, a_r
  V = Vn;
}

// ---------- GEMM: z1[b*Ct+tt][c] = sum_k batch[b][t0+tt][k] * W1[c][k] ----------
// tile: 128 rows x 100 cols, K-tile 16. 256 threads, per-thread 2 rows x 25 cols.
__global__ __launch_bounds__(256) void gemm_z1(const float* __restrict__ batch,
                                               const float* __restrict__ W1,
                                               float* __restrict__ z1,
                                               int t0, int Ct, int M) {
  __shared__ float As[16][128];
  __shared__ float Bs[100][16];
  const int tid = threadIdx.x;
  const int r = tid & 63;
  const int g = tid >> 6;
  const int c0 = g * 25;
  const int row0 = blockIdx.x * 128;

  // A staging: f in {tid, tid+256}; row = f>>2 (0..127), kq = f&3 (16 k per row)
  int fr0 = row0 + (tid >> 2);
  int fr1 = fr0 + 64;
  int cr0 = fr0 < M ? fr0 : (M - 1);
  int cr1 = fr1 < M ? fr1 : (M - 1);
  const float* srcA0 = batch + ((size_t)(cr0 / Ct) * TT + t0 + (cr0 % Ct)) * KIN + (tid & 3) * 4;
  const float* srcA1 = batch + ((size_t)(cr1 / Ct) * TT + t0 + (cr1 % Ct)) * KIN + (tid & 3) * 4;
  // B staging: f = tid -> c = tid>>2 (0..63); f = tid+256 (tid<144) -> c 64..99
  const float* srcB0 = W1 + (size_t)(tid >> 2) * KIN + (tid & 3) * 4;
  const bool hasB1 = (tid < 144);
  const float* srcB1 = W1 + (size_t)((tid >> 2) + 64) * KIN + (tid & 3) * 4;

  float acc[50];
#pragma unroll
  for (int i = 0; i < 50; ++i) acc[i] = 0.0f;

  for (int kt = 0; kt < KIN; kt += 16) {
    float4 a0 = *(const float4*)(srcA0 + kt);
    float4 a1 = *(const float4*)(srcA1 + kt);
    float4 b0 = *(const float4*)(srcB0 + kt);
    float4 b1 = make_float4(0.f, 0.f, 0.f, 0.f);
    if (hasB1) b1 = *(const float4*)(srcB1 + kt);
    __syncthreads();   // previous compute done before overwrite
    {
      int kq4 = (tid & 3) * 4;
      int wr = tid >> 2;
      As[kq4 + 0][wr] = a0.x; As[kq4 + 1][wr] = a0.y;
      As[kq4 + 2][wr] = a0.z; As[kq4 + 3][wr] = a0.w;
      As[kq4 + 0][wr + 64] = a1.x; As[kq4 + 1][wr + 64] = a1.y;
      As[kq4 + 2][wr + 64] = a1.z; As[kq4 + 3][wr + 64] = a1.w;
      *(float4*)&Bs[wr][kq4] = b0;
      if (hasB1) *(float4*)&Bs[wr + 64][kq4] = b1;
    }
    __syncthreads();
#pragma unroll
    for (int kk = 0; kk < 16; kk += 4) {
      float a0r[4], a1r[4];
#pragma unroll
      for (int i = 0; i < 4; ++i) { a0r[i] = As[kk + i][r]; a1r[i] = As[kk + i][r + 64]; }
#pragma unroll
      for (int j = 0; j < 25; ++j) {
        float4 bv = *(const float4*)&Bs[c0 + j][kk];
        acc[j]      += a0r[0] * bv.x; acc[j]      += a0r[1] * bv.y;
        acc[j]      += a0r[2] * bv.z; acc[j]      += a0r[3] * bv.w;
        acc[25 + j] += a1r[0] * bv.x; acc[25 + j] += a1r[1] * bv.y;
        acc[25 + j] += a1r[2] * bv.z; acc[25 + j] += a1r[3] * bv.w;
      }
    }
  }
  int rg0 = row0 + r, rg1 = row0 + r + 64;
  if (rg0 < M) {
    float* dst = z1 + (size_t)rg0 * 100 + c0;
#pragma unroll
    for (int j = 0; j < 25; ++j) dst[j] = acc[j];
  }
  if (rg1 < M) {
    float* dst = z1 + (size_t)rg1 * 100 + c0;
#pragma unroll
    for (int j = 0; j < 25; ++j) dst[j] = acc[25 + j];
  }
}

// ---------- fused two-layer HH scan ----------
// 1 block per batch element. 192 threads = 3 waves.
// wave0+wave1 lanes 0..99: layer-1 neurons. wave2 (tid 128..167): layer 2,
// 4 lanes per output (o = u>>2, j = u&3), each sums 25 T1*W2 terms + shfl reduce.
// Raw s_barrier (lgkmcnt-only drain) keeps z1 prefetch loads in flight.
__global__ __launch_bounds__(192) void hh_scan(const float* __restrict__ z1buf,
                                               const float* __restrict__ W2,
                                               float* __restrict__ out,
                                               float* __restrict__ st,
                                               int t0, int Ct) {
  const int b = blockIdx.x;
  const int tid = threadIdx.x;
  __shared__ float T1buf[2][112];
  const int k0 = t0 + 1;
  const int k1 = t0 + Ct + 1;

  float* SV1 = st;            float* SM1 = st + 10000;
  float* SN1 = st + 20000;    float* SH1 = st + 30000;
  float* SY1 = st + 40000;    float* SV2 = st + 50000;
  float* SM2 = st + 51000;    float* SN2 = st + 52000;
  float* SH2 = st + 53000;    float* SY2 = st + 54000;
  float* ST1 = st + 55000;

  // ---- layer-1 setup ----
  float V1 = 0.f, m1 = 0.f, n1 = 0.f, h1 = 0.f, y1 = 0.f, T1v = 0.f;
  const float* zrow = nullptr;
  float z_cur = 0.f, z_nx1 = 0.f;
  if (tid < N1) {
    if (t0 == 0) { V1 = -70.0f; m1 = 0.f; n1 = 0.f; h1 = 1.0f; y1 = 0.0f; T1v = sigmoid3(-70.0f); }
    else {
      int ix = b * N1 + tid;
      V1 = SV1[ix]; m1 = SM1[ix]; n1 = SN1[ix]; h1 = SH1[ix]; y1 = SY1[ix]; T1v = ST1[ix];
    }
    T1buf[(k0 - 1) & 1][tid] = T1v;
    zrow = z1buf + (size_t)b * Ct * 100 + tid;
    z_cur = zrow[0];
    z_nx1 = (Ct > 1) ? zrow[100] : 0.0f;
  }
  // ---- layer-2 setup ----
  float V2 = 0.f, m2 = 0.f, n2 = 0.f, h2 = 0.f, y2 = 0.f;
  float w2r[25];
  int o = 0, jj = 0;
  bool l2 = false;
  if (tid >= 128 && tid < 168) {
    l2 = true;
    int u = tid - 128;
    o = u >> 2; jj = u & 3;
#pragma unroll
    for (int i = 0; i < 25; ++i) w2r[i] = W2[o * 100 + jj * 25 + i];
    if (t0 == 0) {
      V2 = -70.0f; m2 = 0.f; n2 = 0.f; h2 = 1.0f; y2 = 1.0f;
      if (jj == 0) out[(size_t)b * TT * 10 + o] = sigmoid3(-70.0f);
    } else {
      int ix = b * N2 + o;
      V2 = SV2[ix]; m2 = SM2[ix]; n2 = SN2[ix]; h2 = SH2[ix]; y2 = SY2[ix];
    }
  }
  asm volatile("s_waitcnt lgkmcnt(0)\n\ts_barrier" ::: "memory");

  for (int k = k0; k < k1; ++k) {
    const int ph = k & 1;
    if (tid < N1) {
      float z_nx2 = 0.0f;
      if (k + 2 < k1) z_nx2 = zrow[(size_t)(k + 2 - k0) * 100];   // distance-2 prefetch
      hh_step(V1, m1, n1, h1, y1, z_cur);
      T1v = sigmoid3(V1);
      T1buf[ph][tid] = T1v;
      z_cur = z_nx1; z_nx1 = z_nx2;
    }
    if (l2) {
      const float* tp = T1buf[ph ^ 1];
      float s = 0.0f;
#pragma unroll
      for (int i = 0; i < 25; ++i) s += tp[jj * 25 + i] * w2r[i];
      s += __shfl_xor(s, 1);
      s += __shfl_xor(s, 2);
      hh_step(V2, m2, n2, h2, y2, s);
      if (jj == 0) out[((size_t)b * TT + k) * 10 + o] = sigmoid3(V2);
    }
    asm volatile("s_waitcnt lgkmcnt(0)\n\ts_barrier" ::: "memory");
  }

  if (tid < N1) {
    int ix = b * N1 + tid;
    SV1[ix] = V1; SM1[ix] = m1; SN1[ix] = n1; SH1[ix] = h1; SY1[ix] = y1; ST1[ix] = T1v;
  }
  if (l2 && jj == 0) {
    int ix = b * N2 + o;
    SV2[ix] = V2; SM2[ix] = m2; SN2[ix] = n2; SH2[ix] = h2; SY2[ix] = y2;
  }
}

extern "C" void kernel_launch(void* const* d_in, const int* in_sizes, int n_in,
                              void* d_out, int out_size, void* d_ws, size_t ws_size,
                              hipStream_t stream) {
  (void)in_sizes; (void)n_in; (void)out_size;
  const float* batch = (const float*)d_in[0];
  const float* W1 = (const float*)d_in[1];
  const float* W2 = (const float*)d_in[2];
  float* out = (float*)d_out;

  const size_t state_bytes = 65000u * 4u;
  size_t avail = (ws_size > state_bytes + 4096) ? (ws_size - state_bytes - 4096) : 0;
  long long Cll = (long long)(avail / (100ull * 100ull * 4ull));   // z rows that fit
  int C = (int)(Cll > 1999 ? 1999 : Cll);
  if (C < 1) C = 1;   // assume ws_size is at least ~300 KB

  float* z1buf = (float*)d_ws;
  size_t zbytes = (((size_t)C * 100 * 100 * 4) + 255) & ~(size_t)255;
  float* st = (float*)((char*)d_ws + zbytes);

  for (int t0 = 0; t0 < TT - 1; t0 += C) {
    int Ct = (TT - 1) - t0;
    if (Ct > C) Ct = C;
    int M = NBATCH * Ct;
    dim3 gg((unsigned)((M + 127) / 128));
    gemm_z1<<<gg, dim3(256), 0, stream>>>(batch, W1, z1buf, t0, Ct, M);
    hh_scan<<<dim3(NBATCH), dim3(192), 0, stream>>>(z1buf, W2, out, st, t0, Ct);
  }
}